// Round 8
// baseline (155.738 us; speedup 1.0000x reference)
//
#include <hip/hip_runtime.h>
#include <hip/hip_bf16.h>

typedef __attribute__((ext_vector_type(8)))  _Float16 half8;
typedef __attribute__((ext_vector_type(2)))  _Float16 half2v;
typedef __attribute__((ext_vector_type(16))) float f32x16;
typedef __attribute__((ext_vector_type(4)))  unsigned int uint4v;
typedef __attribute__((ext_vector_type(2)))  unsigned int uint2v;
typedef unsigned int   uint32;
typedef unsigned short u16;

#define DEV __device__ __forceinline__

constexpr int S   = 2048;
constexpr int D   = 128;
constexpr int BH  = 32;
constexpr int QB  = 128;      // q rows per block (4 q-waves x 32)
constexpr int KVG = 32;       // kv rows per tile per group
constexpr int NTG = (S / 2) / KVG;  // 32 tiles per group (each group: half of KV)
constexpr float LOG2E = 1.4426950408889634f;
constexpr size_t WS_NEED = (size_t)2 * BH * S * D * sizeof(u16);  // Kh + Vt

DEV uint32 pk2(float a, float b) {
  half2v h = { (_Float16)a, (_Float16)b };
  return __builtin_bit_cast(uint32, h);
}
DEV u16 tof16(float a) {
  _Float16 h = (_Float16)a;
  return __builtin_bit_cast(u16, h);
}
DEV float f4c(const float4& v, int c) {
  return c == 0 ? v.x : c == 1 ? v.y : c == 2 ? v.z : v.w;
}
DEV float partner32(float x, int h) {
  uint2v r = __builtin_amdgcn_permlane32_swap(
      __builtin_bit_cast(uint32, x), __builtin_bit_cast(uint32, x), false, false);
  return __builtin_bit_cast(float, h ? r[0] : r[1]);
}
DEV void gl2lds16(const void* g, void* l) {  // 16B direct global->LDS DMA
  __builtin_amdgcn_global_load_lds(
      (const __attribute__((address_space(1))) void*)g,
      (__attribute__((address_space(3))) void*)l, 16, 0, 0);
}

// ---------- prepass 1: K fp32 -> fp16 flat ----------
__global__ __launch_bounds__(256)
void k_to_half(const float* __restrict__ Kg, u16* __restrict__ Kh) {
  const int n4 = BH * S * D / 4;
  for (int i = blockIdx.x * 256 + threadIdx.x; i < n4; i += gridDim.x * 256) {
    float4 v = ((const float4*)Kg)[i];
    uint2v p = { pk2(v.x, v.y), pk2(v.z, v.w) };
    *(uint2v*)(Kh + (size_t)i * 4) = p;
  }
}

// ---------- prepass 2: V fp32 [bh][s][d] -> fp16 Vt [bh][d][s] ----------
__global__ __launch_bounds__(256)
void v_transpose(const float* __restrict__ Vg, u16* __restrict__ Vt) {
  __shared__ u16 tile[64][72];  // padded
  const int tid = threadIdx.x;
  int b = blockIdx.x;
  const int dt = b & 1;  b >>= 1;   // d tile [0,2)
  const int st = b & 31; b >>= 5;   // s tile [0,32)
  const int bh = b;                 // [0,32)
  const int s0 = st * 64, d0 = dt * 64;
  const float* Vb = Vg + (size_t)bh * S * D;
  const int j = tid & 63;
  #pragma unroll
  for (int ii = 0; ii < 16; ++ii) {
    const int i = (tid >> 6) * 16 + ii;
    tile[i][j] = tof16(Vb[(size_t)(s0 + i) * D + d0 + j]);
  }
  __syncthreads();
  u16* Vtb = Vt + (size_t)bh * D * S;
  const int jd = tid >> 2;   // d offset [0,64)
  const int q  = tid & 3;    // s quarter
  #pragma unroll
  for (int s4 = 0; s4 < 4; ++s4) {
    const int si = q * 16 + s4 * 4;
    uint2v pv = { (uint32)tile[si + 0][jd] | ((uint32)tile[si + 1][jd] << 16),
                  (uint32)tile[si + 2][jd] | ((uint32)tile[si + 3][jd] << 16) };
    *(uint2v*)(Vtb + (size_t)(d0 + jd) * S + s0 + si) = pv;
  }
}

// ---------- main: split-KV flash attention, 8 waves (2 kv-groups x 4 q-waves) ----------
// mfma_f32_32x32x16_f16: A row=l&31,k=(l>>5)*8+j; B col=l&31,same k;
// C/D col=l&31, row=(r&3)+8*(r>>2)+4*(l>>5).  S^T = K*Q^T, softmax in-register.
// Group g = w>>2 handles kv in [g*1024,(g+1)*1024), KVG=32 per tile.
// LDS tiles [32][256B], 16 granules, XOR-swizzle gran^(row&15) (conflict-free).
// V^T folded: element (d,s_in_tile) -> row d&31, granule (d>>5)*4 + s/8.
// Epilogue: flash-combine of the two groups via LDS (log2 domain).
// Q pre-scaled by LOG2E (scores in log2 domain).
__global__ __launch_bounds__(512, 4)
void attn_fwd(const float* __restrict__ Qg, const u16* __restrict__ Kh,
              const u16* __restrict__ Vt, float* __restrict__ Og) {
  __shared__ __align__(16) char kb[2][2][32 * 256];   // [group][buf] K tile
  __shared__ __align__(16) char vb[2][2][32 * 256];   // [group][buf] V^T tile

  const int tid  = threadIdx.x;
  const int w    = tid >> 6;
  const int l    = tid & 63;
  const int lo   = l & 31;
  const int h    = l >> 5;
  const int g    = w >> 2;        // kv group
  const int wq   = w & 3;         // q-wave within group
  const int ltid = tid & 255;     // id within group
  const int sg   = ltid & 15;     // staging granule
  const int kvbase = g << 10;     // g * 1024

  const int idb = blockIdx.x;
  const int swz = (idb & 7) * 64 + (idb >> 3);
  const int bh  = swz >> 4;   // [0,32)
  const int qb  = swz & 15;   // [0,16)

  const size_t base = (size_t)bh * S * D;
  const float4* __restrict__ Q4 = (const float4*)(Qg + base);
  const u16* __restrict__ Ks = Kh + base;            // [s][d] halfs
  const u16* __restrict__ Vs = Vt + base;            // [d][s] halfs

  // ---- Q fragments, pre-scaled by LOG2E ----
  half8 qf[8];
  {
    const int q = qb * QB + wq * 32 + lo;
    #pragma unroll
    for (int kc = 0; kc < 8; ++kc) {
      const int f4 = q * 32 + kc * 4 + h * 2;
      float4 a = Q4[f4];
      float4 b = Q4[f4 + 1];
      uint4v uu = { pk2(a.x * LOG2E, a.y * LOG2E), pk2(a.z * LOG2E, a.w * LOG2E),
                    pk2(b.x * LOG2E, b.y * LOG2E), pk2(b.z * LOG2E, b.w * LOG2E) };
      qf[kc] = __builtin_bit_cast(half8, uu);
    }
  }

  f32x16 acc0 = {}, acc1 = {}, acc2 = {}, acc3 = {};
  float m_run = -3.0e38f, l_run = 0.f;

  auto stage = [&](int t, int bsel) {
    const int kv0 = kvbase + t * KVG;
    char* kd = kb[g][bsel] + wq * 1024;
    char* vd = vb[g][bsel] + wq * 1024;
    #pragma unroll
    for (int i = 0; i < 2; ++i) {
      const int r  = i * 16 + (ltid >> 4);
      const int gu = sg ^ (r & 15);
      gl2lds16(Ks + (size_t)(kv0 + r) * D + gu * 8, kd + i * 4096);
    }
    #pragma unroll
    for (int i = 0; i < 2; ++i) {
      const int r  = i * 16 + (ltid >> 4);
      const int gu = sg ^ (r & 15);
      const int d  = r + ((gu >> 2) << 5);   // fold: d = row + 32*(gu>>2)
      gl2lds16(Vs + (size_t)d * S + kv0 + ((gu & 3) << 3), vd + i * 4096);
    }
  };

  stage(0, 0);
  stage(1, 1);
  asm volatile("s_waitcnt vmcnt(0)" ::: "memory");
  __syncthreads();

  for (int t = 0; t < NTG; ++t) {
    const int cur = t & 1;
    const char* kcur = kb[g][cur];
    const char* vcur = vb[g][cur];

    // ---- S^T = K * Q^T (32 kv x 32 q) ----
    f32x16 st = {};
    __builtin_amdgcn_s_setprio(1);
    #pragma unroll
    for (int kc = 0; kc < 8; ++kc) {
      const int boff = kc * 32 + h * 16;
      half8 kf = *(const half8*)(kcur + lo * 256 + (boff ^ ((lo & 15) << 4)));
      st = __builtin_amdgcn_mfma_f32_32x32x16_f16(kf, qf[kc], st, 0, 0, 0);
    }
    __builtin_amdgcn_s_setprio(0);

    // ---- online softmax (log2 domain; lane pair {l, l^32}) ----
    float mA = st[0], mB = st[1], mC = st[2], mD = st[3];
    #pragma unroll
    for (int r = 4; r < 16; r += 4) {
      mA = fmaxf(mA, st[r]);   mB = fmaxf(mB, st[r+1]);
      mC = fmaxf(mC, st[r+2]); mD = fmaxf(mD, st[r+3]);
    }
    float mloc = fmaxf(fmaxf(mA, mB), fmaxf(mC, mD));
    mloc = fmaxf(mloc, partner32(mloc, h));

    if (!__all(mloc - m_run <= 8.0f)) {   // defer-max (T13): P <= 2^8, f16-safe
      const float m_new = fmaxf(m_run, mloc);
      const float alpha = exp2f(m_run - m_new);
      l_run *= alpha;
      #pragma unroll
      for (int r = 0; r < 16; ++r) {
        acc0[r] *= alpha; acc1[r] *= alpha; acc2[r] *= alpha; acc3[r] *= alpha;
      }
      m_run = m_new;
    }
    const float mm = m_run;

    float sA = 0.f, sB = 0.f, sC = 0.f, sD = 0.f;
    #pragma unroll
    for (int r = 0; r < 16; r += 4) {
      st[r]   = exp2f(st[r]   - mm); sA += st[r];
      st[r+1] = exp2f(st[r+1] - mm); sB += st[r+1];
      st[r+2] = exp2f(st[r+2] - mm); sC += st[r+2];
      st[r+3] = exp2f(st[r+3] - mm); sD += st[r+3];
    }
    float lsum = (sA + sB) + (sC + sD);
    lsum += partner32(lsum, h);
    l_run += lsum;

    // ---- P^T -> f16 B-frags (permlane32_swap fills two words) ----
    half8 pb[2];
    {
      uint32 u01 = pk2(st[0], st[1]),  u23 = pk2(st[2], st[3]);
      uint32 v01 = pk2(st[4], st[5]),  v23 = pk2(st[6], st[7]);
      uint2v r01 = __builtin_amdgcn_permlane32_swap(u01, v01, false, false);
      uint2v r23 = __builtin_amdgcn_permlane32_swap(u23, v23, false, false);
      uint4v uu = { r01[0], r23[0], r01[1], r23[1] };
      pb[0] = __builtin_bit_cast(half8, uu);
      uint32 x01 = pk2(st[8], st[9]),  x23 = pk2(st[10], st[11]);
      uint32 y01 = pk2(st[12], st[13]), y23 = pk2(st[14], st[15]);
      uint2v s01 = __builtin_amdgcn_permlane32_swap(x01, y01, false, false);
      uint2v s23 = __builtin_amdgcn_permlane32_swap(x23, y23, false, false);
      uint4v vv = { s01[0], s23[0], s01[1], s23[1] };
      pb[1] = __builtin_bit_cast(half8, vv);
    }

    // ---- O^T += V^T * P^T ----
    __builtin_amdgcn_s_setprio(1);
    #pragma unroll
    for (int ks = 0; ks < 2; ++ks) {
      #define PVSTEP(DT, ACC) { \
        const int rr  = DT * 32 + lo; \
        const int row = rr & 31; \
        const int gu  = ((rr >> 5) << 2) + ks * 2 + h; \
        half8 vf = *(const half8*)(vcur + row * 256 + ((gu ^ (row & 15)) << 4)); \
        ACC = __builtin_amdgcn_mfma_f32_32x32x16_f16(vf, pb[ks], ACC, 0, 0, 0); }
      PVSTEP(0, acc0) PVSTEP(1, acc1) PVSTEP(2, acc2) PVSTEP(3, acc3)
      #undef PVSTEP
    }
    __builtin_amdgcn_s_setprio(0);

    asm volatile("s_waitcnt vmcnt(0)" ::: "memory");
    __syncthreads();
    if (t + 2 < NTG) stage(t + 2, cur);
  }

  // ---- split-KV merge (flash combine, log2 domain) then store ----
  float* mlb = (float*)vb;   // 2 KB
  float* ab  = (float*)kb;   // 32 KB per phase
  if (g == 1) {
    mlb[ltid * 2]     = m_run;
    mlb[ltid * 2 + 1] = l_run;
    #pragma unroll
    for (int r = 0; r < 16; ++r) {
      ab[r * 256 + ltid]        = acc0[r];
      ab[(16 + r) * 256 + ltid] = acc1[r];
    }
  }
  __syncthreads();
  float a0 = 0.f, a1 = 0.f, rl = 0.f;
  if (g == 0) {
    const float m1 = mlb[ltid * 2], l1 = mlb[ltid * 2 + 1];
    const float m  = fmaxf(m_run, m1);
    a0 = exp2f(m_run - m);
    a1 = exp2f(m1 - m);
    rl = 1.0f / (l_run * a0 + l1 * a1);
    #pragma unroll
    for (int r = 0; r < 16; ++r) {
      acc0[r] = acc0[r] * a0 + ab[r * 256 + ltid] * a1;
      acc1[r] = acc1[r] * a0 + ab[(16 + r) * 256 + ltid] * a1;
    }
  }
  __syncthreads();
  if (g == 1) {
    #pragma unroll
    for (int r = 0; r < 16; ++r) {
      ab[r * 256 + ltid]        = acc2[r];
      ab[(16 + r) * 256 + ltid] = acc3[r];
    }
  }
  __syncthreads();
  if (g == 0) {
    #pragma unroll
    for (int r = 0; r < 16; ++r) {
      acc2[r] = acc2[r] * a0 + ab[r * 256 + ltid] * a1;
      acc3[r] = acc3[r] * a0 + ab[(16 + r) * 256 + ltid] * a1;
    }
    const int q = qb * QB + wq * 32 + lo;
    float* Op = Og + base + (size_t)q * D;
    auto store_dt = [&](int dt, const f32x16& a) {
      #pragma unroll
      for (int rq = 0; rq < 4; ++rq) {
        float4 o = { a[rq*4+0]*rl, a[rq*4+1]*rl, a[rq*4+2]*rl, a[rq*4+3]*rl };
        *(float4*)(Op + dt * 32 + rq * 8 + h * 4) = o;
      }
    };
    store_dt(0, acc0); store_dt(1, acc1); store_dt(2, acc2); store_dt(3, acc3);
  }
}

// ---------- fallback (R4 kernel, passes; used only if ws too small) ----------
__global__ __launch_bounds__(256, 2)
void attn_fwd_fb(const float* __restrict__ Qg, const float* __restrict__ Kg,
                 const float* __restrict__ Vg, float* __restrict__ Og) {
  __shared__ __align__(16) char kb[2][64 * 256];
  __shared__ __align__(16) char vb[2][128 * 128];
  const int tid = threadIdx.x;
  const int w = tid >> 6, l = tid & 63, lo = l & 31, h = l >> 5;
  const int idb = blockIdx.x;
  const int swz = (idb & 7) * 64 + (idb >> 3);
  const int bh = swz >> 4, qb = swz & 15;
  const size_t base = (size_t)bh * S * D;
  const float4* __restrict__ Q4 = (const float4*)(Qg + base);
  const float4* __restrict__ K4 = (const float4*)(Kg + base);
  const float4* __restrict__ V4 = (const float4*)(Vg + base);
  half8 qf[8];
  {
    const int q = qb * 128 + w * 32 + lo;
    #pragma unroll
    for (int kc = 0; kc < 8; ++kc) {
      const int f4 = q * 32 + kc * 4 + h * 2;
      float4 a = Q4[f4]; float4 b = Q4[f4 + 1];
      uint4v uu = { pk2(a.x, a.y), pk2(a.z, a.w), pk2(b.x, b.y), pk2(b.z, b.w) };
      qf[kc] = __builtin_bit_cast(half8, uu);
    }
  }
  f32x16 acc0 = {}, acc1 = {}, acc2 = {}, acc3 = {};
  float m_run = -3.0e38f, l_run = 0.f;
  const int kr = tid & 63, kq = tid >> 6;
  const int vkv4 = (tid & 15) * 4, vdb = tid >> 4;
  float4 kreg[8], vreg[8];
  auto stage_issue = [&](int t) {
    const int r0 = t * 64;
    #pragma unroll
    for (int i = 0; i < 8; ++i) kreg[i] = K4[(r0 + kr) * 32 + kq * 8 + i];
    #pragma unroll
    for (int k = 0; k < 4; ++k)
      #pragma unroll
      for (int i = 0; i < 2; ++i)
        vreg[k * 2 + i] = V4[(r0 + vkv4 + k) * 32 + vdb * 2 + i];
  };
  auto stage_write = [&](int bsel) {
    char* kd = kb[bsel]; char* vd = vb[bsel];
    #pragma unroll
    for (int i2 = 0; i2 < 4; ++i2) {
      const float4 a = kreg[2 * i2], b = kreg[2 * i2 + 1];
      uint4v uu = { pk2(a.x, a.y), pk2(a.z, a.w), pk2(b.x, b.y), pk2(b.z, b.w) };
      *(uint4v*)(kd + kr * 256 + ((kq * 64 + i2 * 16) ^ ((kr & 7) << 4))) = uu;
    }
    #pragma unroll
    for (int p = 0; p < 8; ++p) {
      const int i = p >> 2, c = p & 3;
      const int d = vdb * 8 + p;
      uint2v pv = { pk2(f4c(vreg[0 + i], c), f4c(vreg[2 + i], c)),
                    pk2(f4c(vreg[4 + i], c), f4c(vreg[6 + i], c)) };
      *(uint2v*)(vd + d * 128 + ((vkv4 * 2) ^ ((d & 7) << 4))) = pv;
    }
  };
  stage_issue(0); stage_write(0); __syncthreads();
  for (int t = 0; t < 32; ++t) {
    const char* kcur = kb[t & 1]; const char* vcur = vb[t & 1];
    f32x16 st0 = {}, st1 = {};
    #pragma unroll
    for (int kc = 0; kc < 8; ++kc) {
      const int boff = kc * 32 + h * 16;
      const int sw = (lo & 7) << 4;
      half8 kf0 = *(const half8*)(kcur + lo * 256        + (boff ^ sw));
      half8 kf1 = *(const half8*)(kcur + (32 + lo) * 256 + (boff ^ sw));
      st0 = __builtin_amdgcn_mfma_f32_32x32x16_f16(kf0, qf[kc], st0, 0, 0, 0);
      st1 = __builtin_amdgcn_mfma_f32_32x32x16_f16(kf1, qf[kc], st1, 0, 0, 0);
    }
    if (t + 1 < 32) stage_issue(t + 1);
    float mA = fmaxf(st0[0], st1[0]), mB = fmaxf(st0[1], st1[1]);
    float mC = fmaxf(st0[2], st1[2]), mD = fmaxf(st0[3], st1[3]);
    #pragma unroll
    for (int r = 4; r < 16; r += 4) {
      mA = fmaxf(mA, fmaxf(st0[r],   st1[r]));
      mB = fmaxf(mB, fmaxf(st0[r+1], st1[r+1]));
      mC = fmaxf(mC, fmaxf(st0[r+2], st1[r+2]));
      mD = fmaxf(mD, fmaxf(st0[r+3], st1[r+3]));
    }
    float mloc = fmaxf(fmaxf(mA, mB), fmaxf(mC, mD));
    mloc = fmaxf(mloc, partner32(mloc, h));
    if (!__all(mloc - m_run <= 8.0f)) {
      const float m_new = fmaxf(m_run, mloc);
      const float alpha = exp2f((m_run - m_new) * LOG2E);
      l_run *= alpha;
      #pragma unroll
      for (int r = 0; r < 16; ++r) {
        acc0[r] *= alpha; acc1[r] *= alpha; acc2[r] *= alpha; acc3[r] *= alpha;
      }
      m_run = m_new;
    }
    const float mm = m_run * LOG2E;
    float sA = 0.f, sB = 0.f, sC = 0.f, sD = 0.f;
    #pragma unroll
    for (int r = 0; r < 16; r += 4) {
      st0[r]   = exp2f(st0[r]   * LOG2E - mm); sA += st0[r];
      st0[r+1] = exp2f(st0[r+1] * LOG2E - mm); sB += st0[r+1];
      st0[r+2] = exp2f(st0[r+2] * LOG2E - mm); sC += st0[r+2];
      st0[r+3] = exp2f(st0[r+3] * LOG2E - mm); sD += st0[r+3];
      st1[r]   = exp2f(st1[r]   * LOG2E - mm); sA += st1[r];
      st1[r+1] = exp2f(st1[r+1] * LOG2E - mm); sB += st1[r+1];
      st1[r+2] = exp2f(st1[r+2] * LOG2E - mm); sC += st1[r+2];
      st1[r+3] = exp2f(st1[r+3] * LOG2E - mm); sD += st1[r+3];
    }
    float lsum = (sA + sB) + (sC + sD);
    lsum += partner32(lsum, h);
    l_run += lsum;
    half8 pb[4];
    #define PACK_KS(SRC, RB, DST) { \
      uint32 u01 = pk2(SRC[RB+0], SRC[RB+1]); \
      uint32 u23 = pk2(SRC[RB+2], SRC[RB+3]); \
      uint32 v01 = pk2(SRC[RB+4], SRC[RB+5]); \
      uint32 v23 = pk2(SRC[RB+6], SRC[RB+7]); \
      uint2v r01 = __builtin_amdgcn_permlane32_swap(u01, v01, false, false); \
      uint2v r23 = __builtin_amdgcn_permlane32_swap(u23, v23, false, false); \
      uint4v uu = { r01[0], r23[0], r01[1], r23[1] }; \
      DST = __builtin_bit_cast(half8, uu); }
    PACK_KS(st0, 0, pb[0]) PACK_KS(st0, 8, pb[1])
    PACK_KS(st1, 0, pb[2]) PACK_KS(st1, 8, pb[3])
    #undef PACK_KS
    #pragma unroll
    for (int ks = 0; ks < 4; ++ks) {
      const int boff = ks * 32 + h * 16;
      #define PVSTEP(DT, ACC) { const int rr = DT * 32 + lo; \
        half8 vf = *(const half8*)(vcur + rr * 128 + (boff ^ ((rr & 7) << 4))); \
        ACC = __builtin_amdgcn_mfma_f32_32x32x16_f16(vf, pb[ks], ACC, 0, 0, 0); }
      PVSTEP(0, acc0) PVSTEP(1, acc1) PVSTEP(2, acc2) PVSTEP(3, acc3)
      #undef PVSTEP
    }
    if (t + 1 < 32) stage_write((t + 1) & 1);
    __syncthreads();
  }
  const float rl = 1.0f / l_run;
  const int q = qb * 128 + w * 32 + lo;
  float* Op = Og + base + (size_t)q * D;
  auto store_dt = [&](int dt, const f32x16& a) {
    #pragma unroll
    for (int rq = 0; rq < 4; ++rq) {
      float4 o = { a[rq*4+0]*rl, a[rq*4+1]*rl, a[rq*4+2]*rl, a[rq*4+3]*rl };
      *(float4*)(Op + dt * 32 + rq * 8 + h * 4) = o;
    }
  };
  store_dt(0, acc0); store_dt(1, acc1); store_dt(2, acc2); store_dt(3, acc3);
}

extern "C" void kernel_launch(void* const* d_in, const int* in_sizes, int n_in,
                              void* d_out, int out_size, void* d_ws, size_t ws_size,
                              hipStream_t stream) {
  (void)in_sizes; (void)n_in; (void)out_size;
  const float* Q = (const float*)d_in[0];
  const float* K = (const float*)d_in[1];
  const float* V = (const float*)d_in[2];
  float* O = (float*)d_out;
  if (ws_size >= WS_NEED) {
    u16* Kh = (u16*)d_ws;
    u16* Vt = Kh + (size_t)BH * S * D;
    k_to_half<<<dim3(1024), dim3(256), 0, stream>>>(K, Kh);
    v_transpose<<<dim3(2048), dim3(256), 0, stream>>>(V, Vt);
    attn_fwd<<<dim3(512), dim3(512), 0, stream>>>(Q, Kh, Vt, O);
  } else {
    attn_fwd_fb<<<dim3(512), dim3(256), 0, stream>>>(Q, K, V, O);
  }
}

// Round 9
// 146.176 us; speedup vs baseline: 1.0654x; 1.0654x over previous
//
#include <hip/hip_runtime.h>
#include <hip/hip_bf16.h>

typedef __attribute__((ext_vector_type(8)))  _Float16 half8;
typedef __attribute__((ext_vector_type(2)))  _Float16 half2v;
typedef __attribute__((ext_vector_type(16))) float f32x16;
typedef __attribute__((ext_vector_type(4)))  unsigned int uint4v;
typedef __attribute__((ext_vector_type(2)))  unsigned int uint2v;
typedef unsigned int   uint32;
typedef unsigned short u16;

#define DEV __device__ __forceinline__

constexpr int S   = 2048;
constexpr int D   = 128;
constexpr int BH  = 32;
constexpr int QB  = 128;      // q rows per block (4 q-waves x 32)
constexpr int KVG = 32;       // kv rows per tile per group
constexpr int NTG = (S / 2) / KVG;  // 32 tiles per group (each group: half of KV)
constexpr float LOG2E = 1.4426950408889634f;
constexpr size_t WS_NEED = (size_t)2 * BH * S * D * sizeof(u16);  // Kh + Vt

DEV uint32 pk2(float a, float b) {
  half2v h = { (_Float16)a, (_Float16)b };
  return __builtin_bit_cast(uint32, h);
}
DEV u16 tof16(float a) {
  _Float16 h = (_Float16)a;
  return __builtin_bit_cast(u16, h);
}
DEV float f4c(const float4& v, int c) {
  return c == 0 ? v.x : c == 1 ? v.y : c == 2 ? v.z : v.w;
}
DEV float partner32(float x, int h) {
  uint2v r = __builtin_amdgcn_permlane32_swap(
      __builtin_bit_cast(uint32, x), __builtin_bit_cast(uint32, x), false, false);
  return __builtin_bit_cast(float, h ? r[0] : r[1]);
}
DEV void gl2lds16(const void* g, void* l) {  // 16B direct global->LDS DMA
  __builtin_amdgcn_global_load_lds(
      (const __attribute__((address_space(1))) void*)g,
      (__attribute__((address_space(3))) void*)l, 16, 0, 0);
}

// ---------- prepass 1: K fp32 -> fp16 flat ----------
__global__ __launch_bounds__(256)
void k_to_half(const float* __restrict__ Kg, u16* __restrict__ Kh) {
  const int n4 = BH * S * D / 4;
  for (int i = blockIdx.x * 256 + threadIdx.x; i < n4; i += gridDim.x * 256) {
    float4 v = ((const float4*)Kg)[i];
    uint2v p = { pk2(v.x, v.y), pk2(v.z, v.w) };
    *(uint2v*)(Kh + (size_t)i * 4) = p;
  }
}

// ---------- prepass 2: V fp32 [bh][s][d] -> fp16 Vt [bh][d][s] ----------
__global__ __launch_bounds__(256)
void v_transpose(const float* __restrict__ Vg, u16* __restrict__ Vt) {
  __shared__ u16 tile[64][72];  // padded
  const int tid = threadIdx.x;
  int b = blockIdx.x;
  const int dt = b & 1;  b >>= 1;   // d tile [0,2)
  const int st = b & 31; b >>= 5;   // s tile [0,32)
  const int bh = b;                 // [0,32)
  const int s0 = st * 64, d0 = dt * 64;
  const float* Vb = Vg + (size_t)bh * S * D;
  const int j = tid & 63;
  #pragma unroll
  for (int ii = 0; ii < 16; ++ii) {
    const int i = (tid >> 6) * 16 + ii;
    tile[i][j] = tof16(Vb[(size_t)(s0 + i) * D + d0 + j]);
  }
  __syncthreads();
  u16* Vtb = Vt + (size_t)bh * D * S;
  const int jd = tid >> 2;   // d offset [0,64)
  const int q  = tid & 3;    // s quarter
  #pragma unroll
  for (int s4 = 0; s4 < 4; ++s4) {
    const int si = q * 16 + s4 * 4;
    uint2v pv = { (uint32)tile[si + 0][jd] | ((uint32)tile[si + 1][jd] << 16),
                  (uint32)tile[si + 2][jd] | ((uint32)tile[si + 3][jd] << 16) };
    *(uint2v*)(Vtb + (size_t)(d0 + jd) * S + s0 + si) = pv;
  }
}

// ---------- main: split-KV flash attention, 8 waves (2 kv-groups x 4 q-waves) ----------
// mfma_f32_32x32x16_f16: A row=l&31,k=(l>>5)*8+j; B col=l&31,same k;
// C/D col=l&31, row=(r&3)+8*(r>>2)+4*(l>>5).  S^T = K*Q^T, softmax in-register.
// Group g = w>>2 handles kv in [g*1024,(g+1)*1024), KVG=32 per tile.
// LDS tiles [32][256B], 16 granules, XOR-swizzle gran^(row&15) (conflict-free).
// V^T folded: element (d,s_in_tile) -> row d&31, granule (d>>5)*4 + s/8.
// Epilogue: flash-combine of the two groups via LDS (log2 domain).
// Q pre-scaled by LOG2E (scores in log2 domain).
// __launch_bounds__(512, 2): cap VGPR at 128 (R8's (512,4) capped at 64 ->
// spill: WRITE_SIZE 32->60MB, MfmaUtil 18%). Natural alloc ~110 fits under
// 128 with zero spill; occupancy still 2 blocks/CU = 4 waves/SIMD (LDS-bound).
__global__ __launch_bounds__(512, 2)
void attn_fwd(const float* __restrict__ Qg, const u16* __restrict__ Kh,
              const u16* __restrict__ Vt, float* __restrict__ Og) {
  __shared__ __align__(16) char kb[2][2][32 * 256];   // [group][buf] K tile
  __shared__ __align__(16) char vb[2][2][32 * 256];   // [group][buf] V^T tile

  const int tid  = threadIdx.x;
  const int w    = tid >> 6;
  const int l    = tid & 63;
  const int lo   = l & 31;
  const int h    = l >> 5;
  const int g    = w >> 2;        // kv group
  const int wq   = w & 3;         // q-wave within group
  const int ltid = tid & 255;     // id within group
  const int sg   = ltid & 15;     // staging granule
  const int kvbase = g << 10;     // g * 1024

  const int idb = blockIdx.x;
  const int swz = (idb & 7) * 64 + (idb >> 3);
  const int bh  = swz >> 4;   // [0,32)
  const int qb  = swz & 15;   // [0,16)

  const size_t base = (size_t)bh * S * D;
  const float4* __restrict__ Q4 = (const float4*)(Qg + base);
  const u16* __restrict__ Ks = Kh + base;            // [s][d] halfs
  const u16* __restrict__ Vs = Vt + base;            // [d][s] halfs

  // ---- Q fragments, pre-scaled by LOG2E ----
  half8 qf[8];
  {
    const int q = qb * QB + wq * 32 + lo;
    #pragma unroll
    for (int kc = 0; kc < 8; ++kc) {
      const int f4 = q * 32 + kc * 4 + h * 2;
      float4 a = Q4[f4];
      float4 b = Q4[f4 + 1];
      uint4v uu = { pk2(a.x * LOG2E, a.y * LOG2E), pk2(a.z * LOG2E, a.w * LOG2E),
                    pk2(b.x * LOG2E, b.y * LOG2E), pk2(b.z * LOG2E, b.w * LOG2E) };
      qf[kc] = __builtin_bit_cast(half8, uu);
    }
  }

  f32x16 acc0 = {}, acc1 = {}, acc2 = {}, acc3 = {};
  float m_run = -3.0e38f, l_run = 0.f;

  auto stage = [&](int t, int bsel) {
    const int kv0 = kvbase + t * KVG;
    char* kd = kb[g][bsel] + wq * 1024;
    char* vd = vb[g][bsel] + wq * 1024;
    #pragma unroll
    for (int i = 0; i < 2; ++i) {
      const int r  = i * 16 + (ltid >> 4);
      const int gu = sg ^ (r & 15);
      gl2lds16(Ks + (size_t)(kv0 + r) * D + gu * 8, kd + i * 4096);
    }
    #pragma unroll
    for (int i = 0; i < 2; ++i) {
      const int r  = i * 16 + (ltid >> 4);
      const int gu = sg ^ (r & 15);
      const int d  = r + ((gu >> 2) << 5);   // fold: d = row + 32*(gu>>2)
      gl2lds16(Vs + (size_t)d * S + kv0 + ((gu & 3) << 3), vd + i * 4096);
    }
  };

  stage(0, 0);
  stage(1, 1);
  asm volatile("s_waitcnt vmcnt(0)" ::: "memory");
  __syncthreads();

  for (int t = 0; t < NTG; ++t) {
    const int cur = t & 1;
    const char* kcur = kb[g][cur];
    const char* vcur = vb[g][cur];

    // ---- S^T = K * Q^T (32 kv x 32 q) ----
    f32x16 st = {};
    __builtin_amdgcn_s_setprio(1);
    #pragma unroll
    for (int kc = 0; kc < 8; ++kc) {
      const int boff = kc * 32 + h * 16;
      half8 kf = *(const half8*)(kcur + lo * 256 + (boff ^ ((lo & 15) << 4)));
      st = __builtin_amdgcn_mfma_f32_32x32x16_f16(kf, qf[kc], st, 0, 0, 0);
    }
    __builtin_amdgcn_s_setprio(0);

    // ---- online softmax (log2 domain; lane pair {l, l^32}) ----
    float mA = st[0], mB = st[1], mC = st[2], mD = st[3];
    #pragma unroll
    for (int r = 4; r < 16; r += 4) {
      mA = fmaxf(mA, st[r]);   mB = fmaxf(mB, st[r+1]);
      mC = fmaxf(mC, st[r+2]); mD = fmaxf(mD, st[r+3]);
    }
    float mloc = fmaxf(fmaxf(mA, mB), fmaxf(mC, mD));
    mloc = fmaxf(mloc, partner32(mloc, h));

    if (!__all(mloc - m_run <= 8.0f)) {   // defer-max (T13): P <= 2^8, f16-safe
      const float m_new = fmaxf(m_run, mloc);
      const float alpha = exp2f(m_run - m_new);
      l_run *= alpha;
      #pragma unroll
      for (int r = 0; r < 16; ++r) {
        acc0[r] *= alpha; acc1[r] *= alpha; acc2[r] *= alpha; acc3[r] *= alpha;
      }
      m_run = m_new;
    }
    const float mm = m_run;

    float sA = 0.f, sB = 0.f, sC = 0.f, sD = 0.f;
    #pragma unroll
    for (int r = 0; r < 16; r += 4) {
      st[r]   = exp2f(st[r]   - mm); sA += st[r];
      st[r+1] = exp2f(st[r+1] - mm); sB += st[r+1];
      st[r+2] = exp2f(st[r+2] - mm); sC += st[r+2];
      st[r+3] = exp2f(st[r+3] - mm); sD += st[r+3];
    }
    float lsum = (sA + sB) + (sC + sD);
    lsum += partner32(lsum, h);
    l_run += lsum;

    // ---- P^T -> f16 B-frags (permlane32_swap fills two words) ----
    half8 pb[2];
    {
      uint32 u01 = pk2(st[0], st[1]),  u23 = pk2(st[2], st[3]);
      uint32 v01 = pk2(st[4], st[5]),  v23 = pk2(st[6], st[7]);
      uint2v r01 = __builtin_amdgcn_permlane32_swap(u01, v01, false, false);
      uint2v r23 = __builtin_amdgcn_permlane32_swap(u23, v23, false, false);
      uint4v uu = { r01[0], r23[0], r01[1], r23[1] };
      pb[0] = __builtin_bit_cast(half8, uu);
      uint32 x01 = pk2(st[8], st[9]),  x23 = pk2(st[10], st[11]);
      uint32 y01 = pk2(st[12], st[13]), y23 = pk2(st[14], st[15]);
      uint2v s01 = __builtin_amdgcn_permlane32_swap(x01, y01, false, false);
      uint2v s23 = __builtin_amdgcn_permlane32_swap(x23, y23, false, false);
      uint4v vv = { s01[0], s23[0], s01[1], s23[1] };
      pb[1] = __builtin_bit_cast(half8, vv);
    }

    // ---- O^T += V^T * P^T ----
    __builtin_amdgcn_s_setprio(1);
    #pragma unroll
    for (int ks = 0; ks < 2; ++ks) {
      #define PVSTEP(DT, ACC) { \
        const int rr  = DT * 32 + lo; \
        const int row = rr & 31; \
        const int gu  = ((rr >> 5) << 2) + ks * 2 + h; \
        half8 vf = *(const half8*)(vcur + row * 256 + ((gu ^ (row & 15)) << 4)); \
        ACC = __builtin_amdgcn_mfma_f32_32x32x16_f16(vf, pb[ks], ACC, 0, 0, 0); }
      PVSTEP(0, acc0) PVSTEP(1, acc1) PVSTEP(2, acc2) PVSTEP(3, acc3)
      #undef PVSTEP
    }
    __builtin_amdgcn_s_setprio(0);

    asm volatile("s_waitcnt vmcnt(0)" ::: "memory");
    __syncthreads();
    if (t + 2 < NTG) stage(t + 2, cur);
  }

  // ---- split-KV merge (flash combine, log2 domain) then store ----
  float* mlb = (float*)vb;   // 2 KB
  float* ab  = (float*)kb;   // 32 KB per phase
  if (g == 1) {
    mlb[ltid * 2]     = m_run;
    mlb[ltid * 2 + 1] = l_run;
    #pragma unroll
    for (int r = 0; r < 16; ++r) {
      ab[r * 256 + ltid]        = acc0[r];
      ab[(16 + r) * 256 + ltid] = acc1[r];
    }
  }
  __syncthreads();
  float a0 = 0.f, a1 = 0.f, rl = 0.f;
  if (g == 0) {
    const float m1 = mlb[ltid * 2], l1 = mlb[ltid * 2 + 1];
    const float m  = fmaxf(m_run, m1);
    a0 = exp2f(m_run - m);
    a1 = exp2f(m1 - m);
    rl = 1.0f / (l_run * a0 + l1 * a1);
    #pragma unroll
    for (int r = 0; r < 16; ++r) {
      acc0[r] = acc0[r] * a0 + ab[r * 256 + ltid] * a1;
      acc1[r] = acc1[r] * a0 + ab[(16 + r) * 256 + ltid] * a1;
    }
  }
  __syncthreads();
  if (g == 1) {
    #pragma unroll
    for (int r = 0; r < 16; ++r) {
      ab[r * 256 + ltid]        = acc2[r];
      ab[(16 + r) * 256 + ltid] = acc3[r];
    }
  }
  __syncthreads();
  if (g == 0) {
    #pragma unroll
    for (int r = 0; r < 16; ++r) {
      acc2[r] = acc2[r] * a0 + ab[r * 256 + ltid] * a1;
      acc3[r] = acc3[r] * a0 + ab[(16 + r) * 256 + ltid] * a1;
    }
    const int q = qb * QB + wq * 32 + lo;
    float* Op = Og + base + (size_t)q * D;
    auto store_dt = [&](int dt, const f32x16& a) {
      #pragma unroll
      for (int rq = 0; rq < 4; ++rq) {
        float4 o = { a[rq*4+0]*rl, a[rq*4+1]*rl, a[rq*4+2]*rl, a[rq*4+3]*rl };
        *(float4*)(Op + dt * 32 + rq * 8 + h * 4) = o;
      }
    };
    store_dt(0, acc0); store_dt(1, acc1); store_dt(2, acc2); store_dt(3, acc3);
  }
}

// ---------- fallback (R4 kernel, passes; used only if ws too small) ----------
__global__ __launch_bounds__(256, 2)
void attn_fwd_fb(const float* __restrict__ Qg, const float* __restrict__ Kg,
                 const float* __restrict__ Vg, float* __restrict__ Og) {
  __shared__ __align__(16) char kb[2][64 * 256];
  __shared__ __align__(16) char vb[2][128 * 128];
  const int tid = threadIdx.x;
  const int w = tid >> 6, l = tid & 63, lo = l & 31, h = l >> 5;
  const int idb = blockIdx.x;
  const int swz = (idb & 7) * 64 + (idb >> 3);
  const int bh = swz >> 4, qb = swz & 15;
  const size_t base = (size_t)bh * S * D;
  const float4* __restrict__ Q4 = (const float4*)(Qg + base);
  const float4* __restrict__ K4 = (const float4*)(Kg + base);
  const float4* __restrict__ V4 = (const float4*)(Vg + base);
  half8 qf[8];
  {
    const int q = qb * 128 + w * 32 + lo;
    #pragma unroll
    for (int kc = 0; kc < 8; ++kc) {
      const int f4 = q * 32 + kc * 4 + h * 2;
      float4 a = Q4[f4]; float4 b = Q4[f4 + 1];
      uint4v uu = { pk2(a.x, a.y), pk2(a.z, a.w), pk2(b.x, b.y), pk2(b.z, b.w) };
      qf[kc] = __builtin_bit_cast(half8, uu);
    }
  }
  f32x16 acc0 = {}, acc1 = {}, acc2 = {}, acc3 = {};
  float m_run = -3.0e38f, l_run = 0.f;
  const int kr = tid & 63, kq = tid >> 6;
  const int vkv4 = (tid & 15) * 4, vdb = tid >> 4;
  float4 kreg[8], vreg[8];
  auto stage_issue = [&](int t) {
    const int r0 = t * 64;
    #pragma unroll
    for (int i = 0; i < 8; ++i) kreg[i] = K4[(r0 + kr) * 32 + kq * 8 + i];
    #pragma unroll
    for (int k = 0; k < 4; ++k)
      #pragma unroll
      for (int i = 0; i < 2; ++i)
        vreg[k * 2 + i] = V4[(r0 + vkv4 + k) * 32 + vdb * 2 + i];
  };
  auto stage_write = [&](int bsel) {
    char* kd = kb[bsel]; char* vd = vb[bsel];
    #pragma unroll
    for (int i2 = 0; i2 < 4; ++i2) {
      const float4 a = kreg[2 * i2], b = kreg[2 * i2 + 1];
      uint4v uu = { pk2(a.x, a.y), pk2(a.z, a.w), pk2(b.x, b.y), pk2(b.z, b.w) };
      *(uint4v*)(kd + kr * 256 + ((kq * 64 + i2 * 16) ^ ((kr & 7) << 4))) = uu;
    }
    #pragma unroll
    for (int p = 0; p < 8; ++p) {
      const int i = p >> 2, c = p & 3;
      const int d = vdb * 8 + p;
      uint2v pv = { pk2(f4c(vreg[0 + i], c), f4c(vreg[2 + i], c)),
                    pk2(f4c(vreg[4 + i], c), f4c(vreg[6 + i], c)) };
      *(uint2v*)(vd + d * 128 + ((vkv4 * 2) ^ ((d & 7) << 4))) = pv;
    }
  };
  stage_issue(0); stage_write(0); __syncthreads();
  for (int t = 0; t < 32; ++t) {
    const char* kcur = kb[t & 1]; const char* vcur = vb[t & 1];
    f32x16 st0 = {}, st1 = {};
    #pragma unroll
    for (int kc = 0; kc < 8; ++kc) {
      const int boff = kc * 32 + h * 16;
      const int sw = (lo & 7) << 4;
      half8 kf0 = *(const half8*)(kcur + lo * 256        + (boff ^ sw));
      half8 kf1 = *(const half8*)(kcur + (32 + lo) * 256 + (boff ^ sw));
      st0 = __builtin_amdgcn_mfma_f32_32x32x16_f16(kf0, qf[kc], st0, 0, 0, 0);
      st1 = __builtin_amdgcn_mfma_f32_32x32x16_f16(kf1, qf[kc], st1, 0, 0, 0);
    }
    if (t + 1 < 32) stage_issue(t + 1);
    float mA = fmaxf(st0[0], st1[0]), mB = fmaxf(st0[1], st1[1]);
    float mC = fmaxf(st0[2], st1[2]), mD = fmaxf(st0[3], st1[3]);
    #pragma unroll
    for (int r = 4; r < 16; r += 4) {
      mA = fmaxf(mA, fmaxf(st0[r],   st1[r]));
      mB = fmaxf(mB, fmaxf(st0[r+1], st1[r+1]));
      mC = fmaxf(mC, fmaxf(st0[r+2], st1[r+2]));
      mD = fmaxf(mD, fmaxf(st0[r+3], st1[r+3]));
    }
    float mloc = fmaxf(fmaxf(mA, mB), fmaxf(mC, mD));
    mloc = fmaxf(mloc, partner32(mloc, h));
    if (!__all(mloc - m_run <= 8.0f)) {
      const float m_new = fmaxf(m_run, mloc);
      const float alpha = exp2f((m_run - m_new) * LOG2E);
      l_run *= alpha;
      #pragma unroll
      for (int r = 0; r < 16; ++r) {
        acc0[r] *= alpha; acc1[r] *= alpha; acc2[r] *= alpha; acc3[r] *= alpha;
      }
      m_run = m_new;
    }
    const float mm = m_run * LOG2E;
    float sA = 0.f, sB = 0.f, sC = 0.f, sD = 0.f;
    #pragma unroll
    for (int r = 0; r < 16; r += 4) {
      st0[r]   = exp2f(st0[r]   * LOG2E - mm); sA += st0[r];
      st0[r+1] = exp2f(st0[r+1] * LOG2E - mm); sB += st0[r+1];
      st0[r+2] = exp2f(st0[r+2] * LOG2E - mm); sC += st0[r+2];
      st0[r+3] = exp2f(st0[r+3] * LOG2E - mm); sD += st0[r+3];
      st1[r]   = exp2f(st1[r]   * LOG2E - mm); sA += st1[r];
      st1[r+1] = exp2f(st1[r+1] * LOG2E - mm); sB += st1[r+1];
      st1[r+2] = exp2f(st1[r+2] * LOG2E - mm); sC += st1[r+2];
      st1[r+3] = exp2f(st1[r+3] * LOG2E - mm); sD += st1[r+3];
    }
    float lsum = (sA + sB) + (sC + sD);
    lsum += partner32(lsum, h);
    l_run += lsum;
    half8 pb[4];
    #define PACK_KS(SRC, RB, DST) { \
      uint32 u01 = pk2(SRC[RB+0], SRC[RB+1]); \
      uint32 u23 = pk2(SRC[RB+2], SRC[RB+3]); \
      uint32 v01 = pk2(SRC[RB+4], SRC[RB+5]); \
      uint32 v23 = pk2(SRC[RB+6], SRC[RB+7]); \
      uint2v r01 = __builtin_amdgcn_permlane32_swap(u01, v01, false, false); \
      uint2v r23 = __builtin_amdgcn_permlane32_swap(u23, v23, false, false); \
      uint4v uu = { r01[0], r23[0], r01[1], r23[1] }; \
      DST = __builtin_bit_cast(half8, uu); }
    PACK_KS(st0, 0, pb[0]) PACK_KS(st0, 8, pb[1])
    PACK_KS(st1, 0, pb[2]) PACK_KS(st1, 8, pb[3])
    #undef PACK_KS
    #pragma unroll
    for (int ks = 0; ks < 4; ++ks) {
      const int boff = ks * 32 + h * 16;
      #define PVSTEP(DT, ACC) { const int rr = DT * 32 + lo; \
        half8 vf = *(const half8*)(vcur + rr * 128 + (boff ^ ((rr & 7) << 4))); \
        ACC = __builtin_amdgcn_mfma_f32_32x32x16_f16(vf, pb[ks], ACC, 0, 0, 0); }
      PVSTEP(0, acc0) PVSTEP(1, acc1) PVSTEP(2, acc2) PVSTEP(3, acc3)
      #undef PVSTEP
    }
    if (t + 1 < 32) stage_write((t + 1) & 1);
    __syncthreads();
  }
  const float rl = 1.0f / l_run;
  const int q = qb * 128 + w * 32 + lo;
  float* Op = Og + base + (size_t)q * D;
  auto store_dt = [&](int dt, const f32x16& a) {
    #pragma unroll
    for (int rq = 0; rq < 4; ++rq) {
      float4 o = { a[rq*4+0]*rl, a[rq*4+1]*rl, a[rq*4+2]*rl, a[rq*4+3]*rl };
      *(float4*)(Op + dt * 32 + rq * 8 + h * 4) = o;
    }
  };
  store_dt(0, acc0); store_dt(1, acc1); store_dt(2, acc2); store_dt(3, acc3);
}

extern "C" void kernel_launch(void* const* d_in, const int* in_sizes, int n_in,
                              void* d_out, int out_size, void* d_ws, size_t ws_size,
                              hipStream_t stream) {
  (void)in_sizes; (void)n_in; (void)out_size;
  const float* Q = (const float*)d_in[0];
  const float* K = (const float*)d_in[1];
  const float* V = (const float*)d_in[2];
  float* O = (float*)d_out;
  if (ws_size >= WS_NEED) {
    u16* Kh = (u16*)d_ws;
    u16* Vt = Kh + (size_t)BH * S * D;
    k_to_half<<<dim3(1024), dim3(256), 0, stream>>>(K, Kh);
    v_transpose<<<dim3(2048), dim3(256), 0, stream>>>(V, Vt);
    attn_fwd<<<dim3(512), dim3(512), 0, stream>>>(Q, Kh, Vt, O);
  } else {
    attn_fwd_fb<<<dim3(512), dim3(256), 0, stream>>>(Q, K, V, O);
  }
}

// Round 11
// 107.520 us; speedup vs baseline: 1.4485x; 1.3595x over previous
//
#include <hip/hip_runtime.h>
#include <hip/hip_bf16.h>

typedef __attribute__((ext_vector_type(8)))  _Float16 half8;
typedef __attribute__((ext_vector_type(2)))  _Float16 half2v;
typedef __attribute__((ext_vector_type(16))) float f32x16;
typedef __attribute__((ext_vector_type(4)))  unsigned int uint4v;
typedef __attribute__((ext_vector_type(2)))  unsigned int uint2v;
typedef unsigned int   uint32;
typedef unsigned short u16;

#define DEV __device__ __forceinline__

constexpr int S   = 2048;
constexpr int D   = 128;
constexpr int BH  = 32;
constexpr int QB  = 128;      // q rows per block (4 waves x 32)
constexpr int KVB = 64;       // kv rows per tile
constexpr int NT  = S / KVB;  // 32
constexpr float LOG2E = 1.4426950408889634f;
constexpr size_t WS_NEED = (size_t)2 * BH * S * D * sizeof(u16);  // Kh + Vt

DEV uint32 pk2(float a, float b) {            // RNE pack (prepass / Q frags)
  half2v h = { (_Float16)a, (_Float16)b };
  return __builtin_bit_cast(uint32, h);
}
DEV uint32 pkrtz(float a, float b) {          // 1-instr packed cvt (P values)
  auto h = __builtin_amdgcn_cvt_pkrtz(a, b);  // __fp16 ext_vector(2)
  return __builtin_bit_cast(uint32, h);
}
// exp2 as a single v_exp_f32 (libm exp2f is a multi-instr OCML call without
// -ffast-math -- it was ~half of the measured VALUBusy).
#if __has_builtin(__builtin_amdgcn_exp2f)
DEV float fexp2(float x) { return __builtin_amdgcn_exp2f(x); }
#else
DEV float fexp2(float x) { float r; asm("v_exp_f32 %0, %1" : "=v"(r) : "v"(x)); return r; }
#endif
DEV u16 tof16(float a) {
  _Float16 h = (_Float16)a;
  return __builtin_bit_cast(u16, h);
}
DEV float f4c(const float4& v, int c) {
  return c == 0 ? v.x : c == 1 ? v.y : c == 2 ? v.z : v.w;
}
DEV float partner32(float x, int h) {
  uint2v r = __builtin_amdgcn_permlane32_swap(
      __builtin_bit_cast(uint32, x), __builtin_bit_cast(uint32, x), false, false);
  return __builtin_bit_cast(float, h ? r[0] : r[1]);
}
DEV void gl2lds16(const void* g, void* l) {  // 16B direct global->LDS DMA
  __builtin_amdgcn_global_load_lds(
      (const __attribute__((address_space(1))) void*)g,
      (__attribute__((address_space(3))) void*)l, 16, 0, 0);
}

// ---------- prepass 1: K fp32 -> fp16 flat ----------
__global__ __launch_bounds__(256)
void k_to_half(const float* __restrict__ Kg, u16* __restrict__ Kh) {
  const int n4 = BH * S * D / 4;
  for (int i = blockIdx.x * 256 + threadIdx.x; i < n4; i += gridDim.x * 256) {
    float4 v = ((const float4*)Kg)[i];
    uint2v p = { pk2(v.x, v.y), pk2(v.z, v.w) };
    *(uint2v*)(Kh + (size_t)i * 4) = p;
  }
}

// ---------- prepass 2: V fp32 [bh][s][d] -> fp16 Vt [bh][d][s] ----------
__global__ __launch_bounds__(256)
void v_transpose(const float* __restrict__ Vg, u16* __restrict__ Vt) {
  __shared__ u16 tile[64][72];  // padded
  const int tid = threadIdx.x;
  int b = blockIdx.x;
  const int dt = b & 1;  b >>= 1;   // d tile [0,2)
  const int st = b & 31; b >>= 5;   // s tile [0,32)
  const int bh = b;                 // [0,32)
  const int s0 = st * 64, d0 = dt * 64;
  const float* Vb = Vg + (size_t)bh * S * D;
  const int j = tid & 63;
  #pragma unroll
  for (int ii = 0; ii < 16; ++ii) {
    const int i = (tid >> 6) * 16 + ii;
    tile[i][j] = tof16(Vb[(size_t)(s0 + i) * D + d0 + j]);
  }
  __syncthreads();
  u16* Vtb = Vt + (size_t)bh * D * S;
  const int jd = tid >> 2;   // d offset [0,64)
  const int q  = tid & 3;    // s quarter
  #pragma unroll
  for (int s4 = 0; s4 < 4; ++s4) {
    const int si = q * 16 + s4 * 4;
    uint2v pv = { (uint32)tile[si + 0][jd] | ((uint32)tile[si + 1][jd] << 16),
                  (uint32)tile[si + 2][jd] | ((uint32)tile[si + 3][jd] << 16) };
    *(uint2v*)(Vtb + (size_t)(d0 + jd) * S + s0 + si) = pv;
  }
}

// ---------- main: flash attention (R6 structure + VALU diet) ----------
// mfma_f32_32x32x16_f16: A row=l&31,k=(l>>5)*8+j; B col=l&31,same k;
// C/D col=l&31, row=(r&3)+8*(r>>2)+4*(l>>5).  S^T = K*Q^T (softmax in-register,
// lane pair {l, l^32}).  Q pre-scaled by LOG2E (scores in log2 domain).
// LDS tiles: 64 rows x 256B (16 granules of 16B), XOR swizzle gran^(row&15)
// (conflict-free, verified BANK_CONFLICT=0).  V^T folded:
// (d,s) -> row d&63, granule (d>>6)*8 + s/8.
__global__ __launch_bounds__(256, 2)
void attn_fwd(const float* __restrict__ Qg, const u16* __restrict__ Kh,
              const u16* __restrict__ Vt, float* __restrict__ Og) {
  __shared__ __align__(16) char kb[2][64 * 256];   // K tile f16 [64][128]
  __shared__ __align__(16) char vb[2][64 * 256];   // V^T tile f16 folded

  const int tid = threadIdx.x;
  const int w  = tid >> 6;
  const int l  = tid & 63;
  const int lo = l & 31;
  const int h  = l >> 5;

  const int idb = blockIdx.x;
  const int swz = (idb & 7) * 64 + (idb >> 3);
  const int bh  = swz >> 4;   // [0,32)
  const int qb  = swz & 15;   // [0,16)

  const size_t base = (size_t)bh * S * D;
  const float4* __restrict__ Q4 = (const float4*)(Qg + base);
  const u16* __restrict__ Ks = Kh + base;            // [s][d] halfs
  const u16* __restrict__ Vs = Vt + base;            // [d][s] halfs

  // ---- Q fragments, pre-scaled by LOG2E ----
  half8 qf[8];
  {
    const int q = qb * QB + w * 32 + lo;
    #pragma unroll
    for (int kc = 0; kc < 8; ++kc) {
      const int f4 = q * 32 + kc * 4 + h * 2;
      float4 a = Q4[f4];
      float4 b = Q4[f4 + 1];
      uint4v uu = { pk2(a.x * LOG2E, a.y * LOG2E), pk2(a.z * LOG2E, a.w * LOG2E),
                    pk2(b.x * LOG2E, b.y * LOG2E), pk2(b.z * LOG2E, b.w * LOG2E) };
      qf[kc] = __builtin_bit_cast(half8, uu);
    }
  }

  f32x16 acc0 = {}, acc1 = {}, acc2 = {}, acc3 = {};
  float m_run = -3.0e38f, l_run = 0.f;

  // staging: 8 x global_load_lds(16B) per thread per tile
  const int srow0 = tid >> 4;  // + i*16 -> LDS row
  const int sg    = tid & 15;  // granule

  auto stage = [&](int t, int bsel) {
    const u16* kt = Ks + (size_t)t * KVB * D;   // K tile base [64][128]
    const u16* vt = Vs + (size_t)t * KVB;       // V^T tile cols, row stride S
    char* kd = kb[bsel] + w * 1024;
    char* vd = vb[bsel] + w * 1024;
    #pragma unroll
    for (int i = 0; i < 4; ++i) {
      const int r  = i * 16 + srow0;
      const int gu = sg ^ (r & 15);
      gl2lds16(kt + r * D + gu * 8, kd + i * 4096);
    }
    #pragma unroll
    for (int i = 0; i < 4; ++i) {
      const int r  = i * 16 + srow0;            // LDS row [0,64)
      const int gu = sg ^ (r & 15);
      const int d  = r + ((gu >> 3) << 6);      // fold: d = row + 64*(gu>=8)
      gl2lds16(vt + (size_t)d * S + ((gu & 7) << 3), vd + i * 4096);
    }
  };

  stage(0, 0);
  stage(1, 1);
  asm volatile("s_waitcnt vmcnt(0)" ::: "memory");
  __syncthreads();

  for (int t = 0; t < NT; ++t) {
    const int cur = t & 1;
    const char* kcur = kb[cur];
    const char* vcur = vb[cur];

    // ---- S^T = K * Q^T ----
    f32x16 st0 = {}, st1 = {};
    __builtin_amdgcn_s_setprio(1);
    #pragma unroll
    for (int kc = 0; kc < 8; ++kc) {
      const int boff = kc * 32 + h * 16;
      const int sw = (lo & 15) << 4;
      half8 kf0 = *(const half8*)(kcur + lo * 256        + (boff ^ sw));
      half8 kf1 = *(const half8*)(kcur + (32 + lo) * 256 + (boff ^ sw));
      st0 = __builtin_amdgcn_mfma_f32_32x32x16_f16(kf0, qf[kc], st0, 0, 0, 0);
      st1 = __builtin_amdgcn_mfma_f32_32x32x16_f16(kf1, qf[kc], st1, 0, 0, 0);
    }
    __builtin_amdgcn_s_setprio(0);

    // ---- online softmax (log2 domain) ----
    float mA = fmaxf(st0[0], st1[0]), mB = fmaxf(st0[1], st1[1]);
    float mC = fmaxf(st0[2], st1[2]), mD = fmaxf(st0[3], st1[3]);
    #pragma unroll
    for (int r = 4; r < 16; r += 4) {
      mA = fmaxf(mA, fmaxf(st0[r],   st1[r]));
      mB = fmaxf(mB, fmaxf(st0[r+1], st1[r+1]));
      mC = fmaxf(mC, fmaxf(st0[r+2], st1[r+2]));
      mD = fmaxf(mD, fmaxf(st0[r+3], st1[r+3]));
    }
    float mloc = fmaxf(fmaxf(mA, mB), fmaxf(mC, mD));
    mloc = fmaxf(mloc, partner32(mloc, h));

    if (!__all(mloc - m_run <= 8.0f)) {   // defer-max (T13): P <= 2^8, f16-safe
      const float m_new = fmaxf(m_run, mloc);
      const float alpha = fexp2(m_run - m_new);
      l_run *= alpha;
      #pragma unroll
      for (int r = 0; r < 16; ++r) {
        acc0[r] *= alpha; acc1[r] *= alpha; acc2[r] *= alpha; acc3[r] *= alpha;
      }
      m_run = m_new;
    }
    const float mm = m_run;

    float sA = 0.f, sB = 0.f, sC = 0.f, sD = 0.f;
    #pragma unroll
    for (int r = 0; r < 16; r += 4) {
      st0[r]   = fexp2(st0[r]   - mm); sA += st0[r];
      st0[r+1] = fexp2(st0[r+1] - mm); sB += st0[r+1];
      st0[r+2] = fexp2(st0[r+2] - mm); sC += st0[r+2];
      st0[r+3] = fexp2(st0[r+3] - mm); sD += st0[r+3];
      st1[r]   = fexp2(st1[r]   - mm); sA += st1[r];
      st1[r+1] = fexp2(st1[r+1] - mm); sB += st1[r+1];
      st1[r+2] = fexp2(st1[r+2] - mm); sC += st1[r+2];
      st1[r+3] = fexp2(st1[r+3] - mm); sD += st1[r+3];
    }
    float lsum = (sA + sB) + (sC + sD);
    lsum += partner32(lsum, h);
    l_run += lsum;

    // ---- P^T -> f16 B-frags (cvt_pkrtz + permlane32_swap) ----
    half8 pb[4];
    #define PACK_KS(SRC, RB, DST) { \
      uint32 u01 = pkrtz(SRC[RB+0], SRC[RB+1]); \
      uint32 u23 = pkrtz(SRC[RB+2], SRC[RB+3]); \
      uint32 v01 = pkrtz(SRC[RB+4], SRC[RB+5]); \
      uint32 v23 = pkrtz(SRC[RB+6], SRC[RB+7]); \
      uint2v r01 = __builtin_amdgcn_permlane32_swap(u01, v01, false, false); \
      uint2v r23 = __builtin_amdgcn_permlane32_swap(u23, v23, false, false); \
      uint4v uu = { r01[0], r23[0], r01[1], r23[1] }; \
      DST = __builtin_bit_cast(half8, uu); }
    PACK_KS(st0, 0, pb[0])
    PACK_KS(st0, 8, pb[1])
    PACK_KS(st1, 0, pb[2])
    PACK_KS(st1, 8, pb[3])
    #undef PACK_KS

    // ---- O^T += V^T * P^T ----
    __builtin_amdgcn_s_setprio(1);
    #pragma unroll
    for (int ks = 0; ks < 4; ++ks) {
      #define PVSTEP(DT, ACC) { \
        const int rr  = DT * 32 + lo; \
        const int row = rr & 63; \
        const int gu  = ((rr >> 6) << 3) + ks * 2 + h; \
        half8 vf = *(const half8*)(vcur + row * 256 + ((gu ^ (row & 15)) << 4)); \
        ACC = __builtin_amdgcn_mfma_f32_32x32x16_f16(vf, pb[ks], ACC, 0, 0, 0); }
      PVSTEP(0, acc0) PVSTEP(1, acc1) PVSTEP(2, acc2) PVSTEP(3, acc3)
      #undef PVSTEP
    }
    __builtin_amdgcn_s_setprio(0);

    // barrier drains vmcnt -> tile t+1 resident; all reads of buf[cur] done
    asm volatile("s_waitcnt vmcnt(0)" ::: "memory");
    __syncthreads();
    if (t + 2 < NT) stage(t + 2, cur);  // overwrite just-finished buffer
  }

  // ---- epilogue ----
  const float rl = 1.0f / l_run;
  const int q = qb * QB + w * 32 + lo;
  float* Op = Og + base + (size_t)q * D;
  auto store_dt = [&](int dt, const f32x16& a) {
    #pragma unroll
    for (int rq = 0; rq < 4; ++rq) {
      float4 o = { a[rq*4+0]*rl, a[rq*4+1]*rl, a[rq*4+2]*rl, a[rq*4+3]*rl };
      *(float4*)(Op + dt * 32 + rq * 8 + h * 4) = o;
    }
  };
  store_dt(0, acc0); store_dt(1, acc1); store_dt(2, acc2); store_dt(3, acc3);
}

// ---------- fallback (R4 kernel, passes; used only if ws too small) ----------
__global__ __launch_bounds__(256, 2)
void attn_fwd_fb(const float* __restrict__ Qg, const float* __restrict__ Kg,
                 const float* __restrict__ Vg, float* __restrict__ Og) {
  __shared__ __align__(16) char kb[2][64 * 256];
  __shared__ __align__(16) char vb[2][128 * 128];
  const int tid = threadIdx.x;
  const int w = tid >> 6, l = tid & 63, lo = l & 31, h = l >> 5;
  const int idb = blockIdx.x;
  const int swz = (idb & 7) * 64 + (idb >> 3);
  const int bh = swz >> 4, qb = swz & 15;
  const size_t base = (size_t)bh * S * D;
  const float4* __restrict__ Q4 = (const float4*)(Qg + base);
  const float4* __restrict__ K4 = (const float4*)(Kg + base);
  const float4* __restrict__ V4 = (const float4*)(Vg + base);
  half8 qf[8];
  {
    const int q = qb * 128 + w * 32 + lo;
    #pragma unroll
    for (int kc = 0; kc < 8; ++kc) {
      const int f4 = q * 32 + kc * 4 + h * 2;
      float4 a = Q4[f4]; float4 b = Q4[f4 + 1];
      uint4v uu = { pk2(a.x, a.y), pk2(a.z, a.w), pk2(b.x, b.y), pk2(b.z, b.w) };
      qf[kc] = __builtin_bit_cast(half8, uu);
    }
  }
  f32x16 acc0 = {}, acc1 = {}, acc2 = {}, acc3 = {};
  float m_run = -3.0e38f, l_run = 0.f;
  const int kr = tid & 63, kq = tid >> 6;
  const int vkv4 = (tid & 15) * 4, vdb = tid >> 4;
  float4 kreg[8], vreg[8];
  auto stage_issue = [&](int t) {
    const int r0 = t * 64;
    #pragma unroll
    for (int i = 0; i < 8; ++i) kreg[i] = K4[(r0 + kr) * 32 + kq * 8 + i];
    #pragma unroll
    for (int k = 0; k < 4; ++k)
      #pragma unroll
      for (int i = 0; i < 2; ++i)
        vreg[k * 2 + i] = V4[(r0 + vkv4 + k) * 32 + vdb * 2 + i];
  };
  auto stage_write = [&](int bsel) {
    char* kd = kb[bsel]; char* vd = vb[bsel];
    #pragma unroll
    for (int i2 = 0; i2 < 4; ++i2) {
      const float4 a = kreg[2 * i2], b = kreg[2 * i2 + 1];
      uint4v uu = { pk2(a.x, a.y), pk2(a.z, a.w), pk2(b.x, b.y), pk2(b.z, b.w) };
      *(uint4v*)(kd + kr * 256 + ((kq * 64 + i2 * 16) ^ ((kr & 7) << 4))) = uu;
    }
    #pragma unroll
    for (int p = 0; p < 8; ++p) {
      const int i = p >> 2, c = p & 3;
      const int d = vdb * 8 + p;
      uint2v pv = { pk2(f4c(vreg[0 + i], c), f4c(vreg[2 + i], c)),
                    pk2(f4c(vreg[4 + i], c), f4c(vreg[6 + i], c)) };
      *(uint2v*)(vd + d * 128 + ((vkv4 * 2) ^ ((d & 7) << 4))) = pv;
    }
  };
  stage_issue(0); stage_write(0); __syncthreads();
  for (int t = 0; t < 32; ++t) {
    const char* kcur = kb[t & 1]; const char* vcur = vb[t & 1];
    f32x16 st0 = {}, st1 = {};
    #pragma unroll
    for (int kc = 0; kc < 8; ++kc) {
      const int boff = kc * 32 + h * 16;
      const int sw = (lo & 7) << 4;
      half8 kf0 = *(const half8*)(kcur + lo * 256        + (boff ^ sw));
      half8 kf1 = *(const half8*)(kcur + (32 + lo) * 256 + (boff ^ sw));
      st0 = __builtin_amdgcn_mfma_f32_32x32x16_f16(kf0, qf[kc], st0, 0, 0, 0);
      st1 = __builtin_amdgcn_mfma_f32_32x32x16_f16(kf1, qf[kc], st1, 0, 0, 0);
    }
    if (t + 1 < 32) stage_issue(t + 1);
    float mA = fmaxf(st0[0], st1[0]), mB = fmaxf(st0[1], st1[1]);
    float mC = fmaxf(st0[2], st1[2]), mD = fmaxf(st0[3], st1[3]);
    #pragma unroll
    for (int r = 4; r < 16; r += 4) {
      mA = fmaxf(mA, fmaxf(st0[r],   st1[r]));
      mB = fmaxf(mB, fmaxf(st0[r+1], st1[r+1]));
      mC = fmaxf(mC, fmaxf(st0[r+2], st1[r+2]));
      mD = fmaxf(mD, fmaxf(st0[r+3], st1[r+3]));
    }
    float mloc = fmaxf(fmaxf(mA, mB), fmaxf(mC, mD));
    mloc = fmaxf(mloc, partner32(mloc, h));
    if (!__all(mloc - m_run <= 8.0f)) {
      const float m_new = fmaxf(m_run, mloc);
      const float alpha = fexp2((m_run - m_new) * LOG2E);
      l_run *= alpha;
      #pragma unroll
      for (int r = 0; r < 16; ++r) {
        acc0[r] *= alpha; acc1[r] *= alpha; acc2[r] *= alpha; acc3[r] *= alpha;
      }
      m_run = m_new;
    }
    const float mm = m_run * LOG2E;
    float sA = 0.f, sB = 0.f, sC = 0.f, sD = 0.f;
    #pragma unroll
    for (int r = 0; r < 16; r += 4) {
      st0[r]   = fexp2(st0[r]   * LOG2E - mm); sA += st0[r];
      st0[r+1] = fexp2(st0[r+1] * LOG2E - mm); sB += st0[r+1];
      st0[r+2] = fexp2(st0[r+2] * LOG2E - mm); sC += st0[r+2];
      st0[r+3] = fexp2(st0[r+3] * LOG2E - mm); sD += st0[r+3];
      st1[r]   = fexp2(st1[r]   * LOG2E - mm); sA += st1[r];
      st1[r+1] = fexp2(st1[r+1] * LOG2E - mm); sB += st1[r+1];
      st1[r+2] = fexp2(st1[r+2] * LOG2E - mm); sC += st1[r+2];
      st1[r+3] = fexp2(st1[r+3] * LOG2E - mm); sD += st1[r+3];
    }
    float lsum = (sA + sB) + (sC + sD);
    lsum += partner32(lsum, h);
    l_run += lsum;
    half8 pb[4];
    #define PACK_KS(SRC, RB, DST) { \
      uint32 u01 = pkrtz(SRC[RB+0], SRC[RB+1]); \
      uint32 u23 = pkrtz(SRC[RB+2], SRC[RB+3]); \
      uint32 v01 = pkrtz(SRC[RB+4], SRC[RB+5]); \
      uint32 v23 = pkrtz(SRC[RB+6], SRC[RB+7]); \
      uint2v r01 = __builtin_amdgcn_permlane32_swap(u01, v01, false, false); \
      uint2v r23 = __builtin_amdgcn_permlane32_swap(u23, v23, false, false); \
      uint4v uu = { r01[0], r23[0], r01[1], r23[1] }; \
      DST = __builtin_bit_cast(half8, uu); }
    PACK_KS(st0, 0, pb[0]) PACK_KS(st0, 8, pb[1])
    PACK_KS(st1, 0, pb[2]) PACK_KS(st1, 8, pb[3])
    #undef PACK_KS
    #pragma unroll
    for (int ks = 0; ks < 4; ++ks) {
      const int boff = ks * 32 + h * 16;
      #define PVSTEP(DT, ACC) { const int rr = DT * 32 + lo; \
        half8 vf = *(const half8*)(vcur + rr * 128 + (boff ^ ((rr & 7) << 4))); \
        ACC = __builtin_amdgcn_mfma_f32_32x32x16_f16(vf, pb[ks], ACC, 0, 0, 0); }
      PVSTEP(0, acc0) PVSTEP(1, acc1) PVSTEP(2, acc2) PVSTEP(3, acc3)
      #undef PVSTEP
    }
    if (t + 1 < 32) stage_write((t + 1) & 1);
    __syncthreads();
  }
  const float rl = 1.0f / l_run;
  const int q = qb * 128 + w * 32 + lo;
  float* Op = Og + base + (size_t)q * D;
  auto store_dt = [&](int dt, const f32x16& a) {
    #pragma unroll
    for (int rq = 0; rq < 4; ++rq) {
      float4 o = { a[rq*4+0]*rl, a[rq*4+1]*rl, a[rq*4+2]*rl, a[rq*4+3]*rl };
      *(float4*)(Op + dt * 32 + rq * 8 + h * 4) = o;
    }
  };
  store_dt(0, acc0); store_dt(1, acc1); store_dt(2, acc2); store_dt(3, acc3);
}

extern "C" void kernel_launch(void* const* d_in, const int* in_sizes, int n_in,
                              void* d_out, int out_size, void* d_ws, size_t ws_size,
                              hipStream_t stream) {
  (void)in_sizes; (void)n_in; (void)out_size;
  const float* Q = (const float*)d_in[0];
  const float* K = (const float*)d_in[1];
  const float* V = (const float*)d_in[2];
  float* O = (float*)d_out;
  if (ws_size >= WS_NEED) {
    u16* Kh = (u16*)d_ws;
    u16* Vt = Kh + (size_t)BH * S * D;
    k_to_half<<<dim3(1024), dim3(256), 0, stream>>>(K, Kh);
    v_transpose<<<dim3(2048), dim3(256), 0, stream>>>(V, Vt);
    attn_fwd<<<dim3(512), dim3(256), 0, stream>>>(Q, Kh, Vt, O);
  } else {
    attn_fwd_fb<<<dim3(512), dim3(256), 0, stream>>>(Q, K, V, O);
  }
}

// Round 12
// 103.805 us; speedup vs baseline: 1.5003x; 1.0358x over previous
//
#include <hip/hip_runtime.h>
#include <hip/hip_bf16.h>

typedef __attribute__((ext_vector_type(8)))  _Float16 half8;
typedef __attribute__((ext_vector_type(2)))  _Float16 half2v;
typedef __attribute__((ext_vector_type(16))) float f32x16;
typedef __attribute__((ext_vector_type(4)))  unsigned int uint4v;
typedef __attribute__((ext_vector_type(2)))  unsigned int uint2v;
typedef unsigned int   uint32;
typedef unsigned short u16;

#define DEV __device__ __forceinline__

constexpr int S   = 2048;
constexpr int D   = 128;
constexpr int BH  = 32;
constexpr int QB  = 128;      // q rows per block (4 waves x 32)
constexpr int KVB = 64;       // kv rows per tile
constexpr int NT  = S / KVB;  // 32
constexpr float LOG2E = 1.4426950408889634f;
constexpr size_t WS_NEED = (size_t)2 * BH * S * D * sizeof(u16);  // Kh + Vt

using lds_char = __attribute__((address_space(3))) const char;
using lds_h8   = __attribute__((address_space(3))) const half8;
template <int N> struct ic { static constexpr int value = N; };

DEV uint32 pk2(float a, float b) {            // RNE pack (prepass / Q frags)
  half2v h = { (_Float16)a, (_Float16)b };
  return __builtin_bit_cast(uint32, h);
}
DEV uint32 pkrtz(float a, float b) {          // 1-instr packed cvt (P values)
  auto h = __builtin_amdgcn_cvt_pkrtz(a, b);  // __fp16 ext_vector(2)
  return __builtin_bit_cast(uint32, h);
}
#if __has_builtin(__builtin_amdgcn_exp2f)
DEV float fexp2(float x) { return __builtin_amdgcn_exp2f(x); }
#else
DEV float fexp2(float x) { float r; asm("v_exp_f32 %0, %1" : "=v"(r) : "v"(x)); return r; }
#endif
DEV float max3f(float a, float b, float c) {  // single v_max3_f32 (T17)
  float d; asm("v_max3_f32 %0, %1, %2, %3" : "=v"(d) : "v"(a), "v"(b), "v"(c));
  return d;
}
DEV u16 tof16(float a) {
  _Float16 h = (_Float16)a;
  return __builtin_bit_cast(u16, h);
}
DEV float f4c(const float4& v, int c) {
  return c == 0 ? v.x : c == 1 ? v.y : c == 2 ? v.z : v.w;
}
DEV float partner32(float x, int h) {
  uint2v r = __builtin_amdgcn_permlane32_swap(
      __builtin_bit_cast(uint32, x), __builtin_bit_cast(uint32, x), false, false);
  return __builtin_bit_cast(float, h ? r[0] : r[1]);
}
DEV void gl2lds16(const void* g, void* l) {  // 16B direct global->LDS DMA
  __builtin_amdgcn_global_load_lds(
      (const __attribute__((address_space(1))) void*)g,
      (__attribute__((address_space(3))) void*)l, 16, 0, 0);
}

// ---------- prepass 1: K fp32 -> fp16 flat ----------
__global__ __launch_bounds__(256)
void k_to_half(const float* __restrict__ Kg, u16* __restrict__ Kh) {
  const int n4 = BH * S * D / 4;
  for (int i = blockIdx.x * 256 + threadIdx.x; i < n4; i += gridDim.x * 256) {
    float4 v = ((const float4*)Kg)[i];
    uint2v p = { pk2(v.x, v.y), pk2(v.z, v.w) };
    *(uint2v*)(Kh + (size_t)i * 4) = p;
  }
}

// ---------- prepass 2: V fp32 [bh][s][d] -> fp16 Vt [bh][d][s] ----------
__global__ __launch_bounds__(256)
void v_transpose(const float* __restrict__ Vg, u16* __restrict__ Vt) {
  __shared__ u16 tile[64][72];  // padded
  const int tid = threadIdx.x;
  int b = blockIdx.x;
  const int dt = b & 1;  b >>= 1;   // d tile [0,2)
  const int st = b & 31; b >>= 5;   // s tile [0,32)
  const int bh = b;                 // [0,32)
  const int s0 = st * 64, d0 = dt * 64;
  const float* Vb = Vg + (size_t)bh * S * D;
  const int j = tid & 63;
  #pragma unroll
  for (int ii = 0; ii < 16; ++ii) {
    const int i = (tid >> 6) * 16 + ii;
    tile[i][j] = tof16(Vb[(size_t)(s0 + i) * D + d0 + j]);
  }
  __syncthreads();
  u16* Vtb = Vt + (size_t)bh * D * S;
  const int jd = tid >> 2;   // d offset [0,64)
  const int q  = tid & 3;    // s quarter
  #pragma unroll
  for (int s4 = 0; s4 < 4; ++s4) {
    const int si = q * 16 + s4 * 4;
    uint2v pv = { (uint32)tile[si + 0][jd] | ((uint32)tile[si + 1][jd] << 16),
                  (uint32)tile[si + 2][jd] | ((uint32)tile[si + 3][jd] << 16) };
    *(uint2v*)(Vtb + (size_t)(d0 + jd) * S + s0 + si) = pv;
  }
}

// ---------- main: flash attention (R11 structure + addr precompute + max3) ----------
// mfma_f32_32x32x16_f16: A row=l&31,k=(l>>5)*8+j; B col=l&31,same k;
// C/D col=l&31, row=(r&3)+8*(r>>2)+4*(l>>5).  S^T = K*Q^T (softmax in-register,
// lane pair {l, l^32}).  Q pre-scaled by LOG2E (scores in log2 domain).
// LDS tiles: 64 rows x 256B (16 granules of 16B), XOR swizzle gran^(row&15)
// (conflict-free, verified BANK_CONFLICT=0).  V^T folded:
// (d,s) -> row d&63, granule (d>>6)*8 + s/8.
// All 32 LDS read addresses are loop-invariant: precomputed once as AS(3)
// pointers; t-loop unrolled x2 so buffer parity folds into ds_read offset imm
// (0 / 16384) -> zero address ALU in the hot loop.
__global__ __launch_bounds__(256, 2)
void attn_fwd(const float* __restrict__ Qg, const u16* __restrict__ Kh,
              const u16* __restrict__ Vt, float* __restrict__ Og) {
  __shared__ __align__(16) char kb[2][64 * 256];   // K tile f16 [64][128]
  __shared__ __align__(16) char vb[2][64 * 256];   // V^T tile f16 folded

  const int tid = threadIdx.x;
  const int w  = tid >> 6;
  const int l  = tid & 63;
  const int lo = l & 31;
  const int h  = l >> 5;

  const int idb = blockIdx.x;
  const int swz = (idb & 7) * 64 + (idb >> 3);
  const int bh  = swz >> 4;   // [0,32)
  const int qb  = swz & 15;   // [0,16)

  const size_t base = (size_t)bh * S * D;
  const float4* __restrict__ Q4 = (const float4*)(Qg + base);
  const u16* __restrict__ Ks = Kh + base;            // [s][d] halfs
  const u16* __restrict__ Vs = Vt + base;            // [d][s] halfs

  // ---- Q fragments, pre-scaled by LOG2E ----
  half8 qf[8];
  {
    const int q = qb * QB + w * 32 + lo;
    #pragma unroll
    for (int kc = 0; kc < 8; ++kc) {
      const int f4 = q * 32 + kc * 4 + h * 2;
      float4 a = Q4[f4];
      float4 b = Q4[f4 + 1];
      uint4v uu = { pk2(a.x * LOG2E, a.y * LOG2E), pk2(a.z * LOG2E, a.w * LOG2E),
                    pk2(b.x * LOG2E, b.y * LOG2E), pk2(b.z * LOG2E, b.w * LOG2E) };
      qf[kc] = __builtin_bit_cast(half8, uu);
    }
  }

  // ---- precomputed LDS read addresses (buffer 0; buffer 1 = +16384 imm) ----
  lds_char* ka[16];
  lds_char* va[16];
  {
    const int sw = (lo & 15) << 4;
    #pragma unroll
    for (int kc = 0; kc < 8; ++kc) {
      const int boff = kc * 32 + h * 16;
      ka[2 * kc]     = (lds_char*)(kb[0] + lo * 256        + (boff ^ sw));
      ka[2 * kc + 1] = (lds_char*)(kb[0] + (32 + lo) * 256 + (boff ^ sw));
    }
    #pragma unroll
    for (int ks = 0; ks < 4; ++ks)
      #pragma unroll
      for (int dt = 0; dt < 4; ++dt) {
        const int rr  = dt * 32 + lo;
        const int row = rr & 63;
        const int gu  = ((rr >> 6) << 3) + ks * 2 + h;
        va[ks * 4 + dt] = (lds_char*)(vb[0] + row * 256 + ((gu ^ (row & 15)) << 4));
      }
  }

  f32x16 acc0 = {}, acc1 = {}, acc2 = {}, acc3 = {};
  float m_run = -3.0e38f, l_run = 0.f;

  // staging: 8 x global_load_lds(16B) per thread per tile
  const int srow0 = tid >> 4;  // + i*16 -> LDS row
  const int sg    = tid & 15;  // granule

  auto stage = [&](int t, int bsel) {
    const u16* kt = Ks + (size_t)t * KVB * D;   // K tile base [64][128]
    const u16* vt = Vs + (size_t)t * KVB;       // V^T tile cols, row stride S
    char* kd = kb[bsel] + w * 1024;
    char* vd = vb[bsel] + w * 1024;
    #pragma unroll
    for (int i = 0; i < 4; ++i) {
      const int r  = i * 16 + srow0;
      const int gu = sg ^ (r & 15);
      gl2lds16(kt + r * D + gu * 8, kd + i * 4096);
    }
    #pragma unroll
    for (int i = 0; i < 4; ++i) {
      const int r  = i * 16 + srow0;            // LDS row [0,64)
      const int gu = sg ^ (r & 15);
      const int d  = r + ((gu >> 3) << 6);      // fold: d = row + 64*(gu>=8)
      gl2lds16(vt + (size_t)d * S + ((gu & 7) << 3), vd + i * 4096);
    }
  };

  stage(0, 0);
  stage(1, 1);
  asm volatile("s_waitcnt vmcnt(0)" ::: "memory");
  __syncthreads();

  auto BODY = [&](int T, auto ofs_tag) {
    constexpr int OFS = decltype(ofs_tag)::value;   // 0 or 16384
    constexpr int CUR = OFS ? 1 : 0;

    // ---- S^T = K * Q^T ----
    f32x16 st0 = {}, st1 = {};
    __builtin_amdgcn_s_setprio(1);
    #pragma unroll
    for (int kc = 0; kc < 8; ++kc) {
      half8 kf0 = *(lds_h8*)(ka[2 * kc]     + OFS);
      half8 kf1 = *(lds_h8*)(ka[2 * kc + 1] + OFS);
      st0 = __builtin_amdgcn_mfma_f32_32x32x16_f16(kf0, qf[kc], st0, 0, 0, 0);
      st1 = __builtin_amdgcn_mfma_f32_32x32x16_f16(kf1, qf[kc], st1, 0, 0, 0);
    }
    __builtin_amdgcn_s_setprio(0);

    // ---- online softmax (log2 domain), max via v_max3 tree ----
    float t0 = max3f(st0[0],  st0[1],  st0[2]);
    float t1 = max3f(st0[3],  st0[4],  st0[5]);
    float t2 = max3f(st0[6],  st0[7],  st0[8]);
    float t3 = max3f(st0[9],  st0[10], st0[11]);
    float t4 = max3f(st0[12], st0[13], st0[14]);
    float t5 = max3f(st0[15], st1[0],  st1[1]);
    float t6 = max3f(st1[2],  st1[3],  st1[4]);
    float t7 = max3f(st1[5],  st1[6],  st1[7]);
    float t8 = max3f(st1[8],  st1[9],  st1[10]);
    float t9 = max3f(st1[11], st1[12], st1[13]);
    float ta = fmaxf(st1[14], st1[15]);
    float u0 = max3f(t0, t1, t2);
    float u1 = max3f(t3, t4, t5);
    float u2 = max3f(t6, t7, t8);
    float u3 = max3f(t9, ta, u0);
    float mloc = max3f(u1, u2, u3);
    mloc = fmaxf(mloc, partner32(mloc, h));

    if (!__all(mloc - m_run <= 8.0f)) {   // defer-max (T13): P <= 2^8, f16-safe
      const float m_new = fmaxf(m_run, mloc);
      const float alpha = fexp2(m_run - m_new);
      l_run *= alpha;
      #pragma unroll
      for (int r = 0; r < 16; ++r) {
        acc0[r] *= alpha; acc1[r] *= alpha; acc2[r] *= alpha; acc3[r] *= alpha;
      }
      m_run = m_new;
    }
    const float mm = m_run;

    float sA = 0.f, sB = 0.f, sC = 0.f, sD = 0.f;
    #pragma unroll
    for (int r = 0; r < 16; r += 4) {
      st0[r]   = fexp2(st0[r]   - mm); sA += st0[r];
      st0[r+1] = fexp2(st0[r+1] - mm); sB += st0[r+1];
      st0[r+2] = fexp2(st0[r+2] - mm); sC += st0[r+2];
      st0[r+3] = fexp2(st0[r+3] - mm); sD += st0[r+3];
      st1[r]   = fexp2(st1[r]   - mm); sA += st1[r];
      st1[r+1] = fexp2(st1[r+1] - mm); sB += st1[r+1];
      st1[r+2] = fexp2(st1[r+2] - mm); sC += st1[r+2];
      st1[r+3] = fexp2(st1[r+3] - mm); sD += st1[r+3];
    }
    float lsum = (sA + sB) + (sC + sD);
    lsum += partner32(lsum, h);
    l_run += lsum;

    // ---- P^T -> f16 B-frags (cvt_pkrtz + permlane32_swap) ----
    half8 pb[4];
    #define PACK_KS(SRC, RB, DST) { \
      uint32 u01 = pkrtz(SRC[RB+0], SRC[RB+1]); \
      uint32 u23 = pkrtz(SRC[RB+2], SRC[RB+3]); \
      uint32 v01 = pkrtz(SRC[RB+4], SRC[RB+5]); \
      uint32 v23 = pkrtz(SRC[RB+6], SRC[RB+7]); \
      uint2v r01 = __builtin_amdgcn_permlane32_swap(u01, v01, false, false); \
      uint2v r23 = __builtin_amdgcn_permlane32_swap(u23, v23, false, false); \
      uint4v uu = { r01[0], r23[0], r01[1], r23[1] }; \
      DST = __builtin_bit_cast(half8, uu); }
    PACK_KS(st0, 0, pb[0])
    PACK_KS(st0, 8, pb[1])
    PACK_KS(st1, 0, pb[2])
    PACK_KS(st1, 8, pb[3])
    #undef PACK_KS

    // ---- O^T += V^T * P^T ----
    __builtin_amdgcn_s_setprio(1);
    #pragma unroll
    for (int ks = 0; ks < 4; ++ks) {
      half8 vf0 = *(lds_h8*)(va[ks * 4 + 0] + OFS);
      acc0 = __builtin_amdgcn_mfma_f32_32x32x16_f16(vf0, pb[ks], acc0, 0, 0, 0);
      half8 vf1 = *(lds_h8*)(va[ks * 4 + 1] + OFS);
      acc1 = __builtin_amdgcn_mfma_f32_32x32x16_f16(vf1, pb[ks], acc1, 0, 0, 0);
      half8 vf2 = *(lds_h8*)(va[ks * 4 + 2] + OFS);
      acc2 = __builtin_amdgcn_mfma_f32_32x32x16_f16(vf2, pb[ks], acc2, 0, 0, 0);
      half8 vf3 = *(lds_h8*)(va[ks * 4 + 3] + OFS);
      acc3 = __builtin_amdgcn_mfma_f32_32x32x16_f16(vf3, pb[ks], acc3, 0, 0, 0);
    }
    __builtin_amdgcn_s_setprio(0);

    // barrier drains vmcnt -> tile T+1 resident; all reads of buf[CUR] done
    asm volatile("s_waitcnt vmcnt(0)" ::: "memory");
    __syncthreads();
    if (T + 2 < NT) stage(T + 2, CUR);  // overwrite just-finished buffer
  };

  for (int t = 0; t < NT; t += 2) {
    BODY(t,     ic<0>{});
    BODY(t + 1, ic<16384>{});
  }

  // ---- epilogue ----
  const float rl = 1.0f / l_run;
  const int q = qb * QB + w * 32 + lo;
  float* Op = Og + base + (size_t)q * D;
  auto store_dt = [&](int dt, const f32x16& a) {
    #pragma unroll
    for (int rq = 0; rq < 4; ++rq) {
      float4 o = { a[rq*4+0]*rl, a[rq*4+1]*rl, a[rq*4+2]*rl, a[rq*4+3]*rl };
      *(float4*)(Op + dt * 32 + rq * 8 + h * 4) = o;
    }
  };
  store_dt(0, acc0); store_dt(1, acc1); store_dt(2, acc2); store_dt(3, acc3);
}

// ---------- fallback (R4 kernel, passes; used only if ws too small) ----------
__global__ __launch_bounds__(256, 2)
void attn_fwd_fb(const float* __restrict__ Qg, const float* __restrict__ Kg,
                 const float* __restrict__ Vg, float* __restrict__ Og) {
  __shared__ __align__(16) char kb[2][64 * 256];
  __shared__ __align__(16) char vb[2][128 * 128];
  const int tid = threadIdx.x;
  const int w = tid >> 6, l = tid & 63, lo = l & 31, h = l >> 5;
  const int idb = blockIdx.x;
  const int swz = (idb & 7) * 64 + (idb >> 3);
  const int bh = swz >> 4, qb = swz & 15;
  const size_t base = (size_t)bh * S * D;
  const float4* __restrict__ Q4 = (const float4*)(Qg + base);
  const float4* __restrict__ K4 = (const float4*)(Kg + base);
  const float4* __restrict__ V4 = (const float4*)(Vg + base);
  half8 qf[8];
  {
    const int q = qb * 128 + w * 32 + lo;
    #pragma unroll
    for (int kc = 0; kc < 8; ++kc) {
      const int f4 = q * 32 + kc * 4 + h * 2;
      float4 a = Q4[f4]; float4 b = Q4[f4 + 1];
      uint4v uu = { pk2(a.x, a.y), pk2(a.z, a.w), pk2(b.x, b.y), pk2(b.z, b.w) };
      qf[kc] = __builtin_bit_cast(half8, uu);
    }
  }
  f32x16 acc0 = {}, acc1 = {}, acc2 = {}, acc3 = {};
  float m_run = -3.0e38f, l_run = 0.f;
  const int kr = tid & 63, kq = tid >> 6;
  const int vkv4 = (tid & 15) * 4, vdb = tid >> 4;
  float4 kreg[8], vreg[8];
  auto stage_issue = [&](int t) {
    const int r0 = t * 64;
    #pragma unroll
    for (int i = 0; i < 8; ++i) kreg[i] = K4[(r0 + kr) * 32 + kq * 8 + i];
    #pragma unroll
    for (int k = 0; k < 4; ++k)
      #pragma unroll
      for (int i = 0; i < 2; ++i)
        vreg[k * 2 + i] = V4[(r0 + vkv4 + k) * 32 + vdb * 2 + i];
  };
  auto stage_write = [&](int bsel) {
    char* kd = kb[bsel]; char* vd = vb[bsel];
    #pragma unroll
    for (int i2 = 0; i2 < 4; ++i2) {
      const float4 a = kreg[2 * i2], b = kreg[2 * i2 + 1];
      uint4v uu = { pk2(a.x, a.y), pk2(a.z, a.w), pk2(b.x, b.y), pk2(b.z, b.w) };
      *(uint4v*)(kd + kr * 256 + ((kq * 64 + i2 * 16) ^ ((kr & 7) << 4))) = uu;
    }
    #pragma unroll
    for (int p = 0; p < 8; ++p) {
      const int i = p >> 2, c = p & 3;
      const int d = vdb * 8 + p;
      uint2v pv = { pk2(f4c(vreg[0 + i], c), f4c(vreg[2 + i], c)),
                    pk2(f4c(vreg[4 + i], c), f4c(vreg[6 + i], c)) };
      *(uint2v*)(vd + d * 128 + ((vkv4 * 2) ^ ((d & 7) << 4))) = pv;
    }
  };
  stage_issue(0); stage_write(0); __syncthreads();
  for (int t = 0; t < 32; ++t) {
    const char* kcur = kb[t & 1]; const char* vcur = vb[t & 1];
    f32x16 st0 = {}, st1 = {};
    #pragma unroll
    for (int kc = 0; kc < 8; ++kc) {
      const int boff = kc * 32 + h * 16;
      const int sw = (lo & 7) << 4;
      half8 kf0 = *(const half8*)(kcur + lo * 256        + (boff ^ sw));
      half8 kf1 = *(const half8*)(kcur + (32 + lo) * 256 + (boff ^ sw));
      st0 = __builtin_amdgcn_mfma_f32_32x32x16_f16(kf0, qf[kc], st0, 0, 0, 0);
      st1 = __builtin_amdgcn_mfma_f32_32x32x16_f16(kf1, qf[kc], st1, 0, 0, 0);
    }
    if (t + 1 < 32) stage_issue(t + 1);
    float mA = fmaxf(st0[0], st1[0]), mB = fmaxf(st0[1], st1[1]);
    float mC = fmaxf(st0[2], st1[2]), mD = fmaxf(st0[3], st1[3]);
    #pragma unroll
    for (int r = 4; r < 16; r += 4) {
      mA = fmaxf(mA, fmaxf(st0[r],   st1[r]));
      mB = fmaxf(mB, fmaxf(st0[r+1], st1[r+1]));
      mC = fmaxf(mC, fmaxf(st0[r+2], st1[r+2]));
      mD = fmaxf(mD, fmaxf(st0[r+3], st1[r+3]));
    }
    float mloc = fmaxf(fmaxf(mA, mB), fmaxf(mC, mD));
    mloc = fmaxf(mloc, partner32(mloc, h));
    if (!__all(mloc - m_run <= 8.0f)) {
      const float m_new = fmaxf(m_run, mloc);
      const float alpha = fexp2((m_run - m_new) * LOG2E);
      l_run *= alpha;
      #pragma unroll
      for (int r = 0; r < 16; ++r) {
        acc0[r] *= alpha; acc1[r] *= alpha; acc2[r] *= alpha; acc3[r] *= alpha;
      }
      m_run = m_new;
    }
    const float mm = m_run * LOG2E;
    float sA = 0.f, sB = 0.f, sC = 0.f, sD = 0.f;
    #pragma unroll
    for (int r = 0; r < 16; r += 4) {
      st0[r]   = fexp2(st0[r]   * LOG2E - mm); sA += st0[r];
      st0[r+1] = fexp2(st0[r+1] * LOG2E - mm); sB += st0[r+1];
      st0[r+2] = fexp2(st0[r+2] * LOG2E - mm); sC += st0[r+2];
      st0[r+3] = fexp2(st0[r+3] * LOG2E - mm); sD += st0[r+3];
      st1[r]   = fexp2(st1[r]   * LOG2E - mm); sA += st1[r];
      st1[r+1] = fexp2(st1[r+1] * LOG2E - mm); sB += st1[r+1];
      st1[r+2] = fexp2(st1[r+2] * LOG2E - mm); sC += st1[r+2];
      st1[r+3] = fexp2(st1[r+3] * LOG2E - mm); sD += st1[r+3];
    }
    float lsum = (sA + sB) + (sC + sD);
    lsum += partner32(lsum, h);
    l_run += lsum;
    half8 pb[4];
    #define PACK_KS(SRC, RB, DST) { \
      uint32 u01 = pkrtz(SRC[RB+0], SRC[RB+1]); \
      uint32 u23 = pkrtz(SRC[RB+2], SRC[RB+3]); \
      uint32 v01 = pkrtz(SRC[RB+4], SRC[RB+5]); \
      uint32 v23 = pkrtz(SRC[RB+6], SRC[RB+7]); \
      uint2v r01 = __builtin_amdgcn_permlane32_swap(u01, v01, false, false); \
      uint2v r23 = __builtin_amdgcn_permlane32_swap(u23, v23, false, false); \
      uint4v uu = { r01[0], r23[0], r01[1], r23[1] }; \
      DST = __builtin_bit_cast(half8, uu); }
    PACK_KS(st0, 0, pb[0]) PACK_KS(st0, 8, pb[1])
    PACK_KS(st1, 0, pb[2]) PACK_KS(st1, 8, pb[3])
    #undef PACK_KS
    #pragma unroll
    for (int ks = 0; ks < 4; ++ks) {
      const int boff = ks * 32 + h * 16;
      #define PVSTEP(DT, ACC) { const int rr = DT * 32 + lo; \
        half8 vf = *(const half8*)(vcur + rr * 128 + (boff ^ ((rr & 7) << 4))); \
        ACC = __builtin_amdgcn_mfma_f32_32x32x16_f16(vf, pb[ks], ACC, 0, 0, 0); }
      PVSTEP(0, acc0) PVSTEP(1, acc1) PVSTEP(2, acc2) PVSTEP(3, acc3)
      #undef PVSTEP
    }
    if (t + 1 < 32) stage_write((t + 1) & 1);
    __syncthreads();
  }
  const float rl = 1.0f / l_run;
  const int q = qb * 128 + w * 32 + lo;
  float* Op = Og + base + (size_t)q * D;
  auto store_dt = [&](int dt, const f32x16& a) {
    #pragma unroll
    for (int rq = 0; rq < 4; ++rq) {
      float4 o = { a[rq*4+0]*rl, a[rq*4+1]*rl, a[rq*4+2]*rl, a[rq*4+3]*rl };
      *(float4*)(Op + dt * 32 + rq * 8 + h * 4) = o;
    }
  };
  store_dt(0, acc0); store_dt(1, acc1); store_dt(2, acc2); store_dt(3, acc3);
}

extern "C" void kernel_launch(void* const* d_in, const int* in_sizes, int n_in,
                              void* d_out, int out_size, void* d_ws, size_t ws_size,
                              hipStream_t stream) {
  (void)in_sizes; (void)n_in; (void)out_size;
  const float* Q = (const float*)d_in[0];
  const float* K = (const float*)d_in[1];
  const float* V = (const float*)d_in[2];
  float* O = (float*)d_out;
  if (ws_size >= WS_NEED) {
    u16* Kh = (u16*)d_ws;
    u16* Vt = Kh + (size_t)BH * S * D;
    k_to_half<<<dim3(1024), dim3(256), 0, stream>>>(K, Kh);
    v_transpose<<<dim3(2048), dim3(256), 0, stream>>>(V, Vt);
    attn_fwd<<<dim3(512), dim3(256), 0, stream>>>(Q, Kh, Vt, O);
  } else {
    attn_fwd_fb<<<dim3(512), dim3(256), 0, stream>>>(Q, K, V, O);
  }
}